// Round 12
// baseline (4004.916 us; speedup 1.0000x reference)
//
#include <hip/hip_runtime.h>
#include <hip/hip_cooperative_groups.h>
#include <cmath>

namespace cg = cooperative_groups;

#define T_STEPS 512
#define NBLK 256
#define FLAG_STRIDE 16  // 64B-padded flag lines; slots 0..7 = per-wave flags

typedef _Float16 h8 __attribute__((ext_vector_type(8)));
typedef float f4 __attribute__((ext_vector_type(4)));
typedef int i32x4 __attribute__((ext_vector_type(4)));
typedef unsigned long long ull_t;

__device__ __forceinline__ float sigm(float v) { return 1.f / (1.f + __expf(-v)); }
__device__ __forceinline__ float tanh_fast(float v) { return 1.f - 2.f / (__expf(2.f * v) + 1.f); }
__device__ __forceinline__ f4 shfl_xor4(f4 v, int m) {
  f4 r;
#pragma unroll
  for (int i = 0; i < 4; i++) r[i] = __shfl_xor(v[i], m, 64);
  return r;
}

// ---------------- pack P = emb @ [Wx interleaved] + bias : [513][4096] fp32 (exact input path)
__global__ void pack_P(const float* __restrict__ emb,
                       const float* __restrict__ Wgx, const float* __restrict__ Wix,
                       const float* __restrict__ Wfx, const float* __restrict__ Wox,
                       const float* __restrict__ bg, const float* __restrict__ bi,
                       const float* __restrict__ bf_, const float* __restrict__ bo,
                       float* __restrict__ P) {
  __shared__ float es[8][512];
  const int vg = blockIdx.x;   // 0..64
  const int st = blockIdx.y;   // 0..15
  const int tid = threadIdx.x;
  for (int i = tid; i < 8 * 512; i += 256) {
    int vv = i >> 9, k = i & 511;
    int v = vg * 8 + vv;
    es[vv][k] = (v < 513) ? emb[v * 512 + k] : 0.f;
  }
  __syncthreads();
  const int c = st * 256 + tid;
  const int gate = c & 3, unit = c >> 2;
  const float* W = gate == 0 ? Wgx : gate == 1 ? Wix : gate == 2 ? Wfx : Wox;
  const float* bias = gate == 0 ? bg : gate == 1 ? bi : gate == 2 ? bf_ : bo;
  float acc[8];
  const float bv = bias[unit];
#pragma unroll
  for (int vv = 0; vv < 8; vv++) acc[vv] = bv;
  for (int k = 0; k < 512; k++) {
    float w = W[k * 1024 + unit];
#pragma unroll
    for (int vv = 0; vv < 8; vv++) acc[vv] += es[vv][k] * w;
  }
#pragma unroll
  for (int vv = 0; vv < 8; vv++) {
    int v = vg * 8 + vv;
    if (v < 513) P[(size_t)v * 4096 + c] = acc[vv];
  }
}

// ---------------- pack Wt[c][k] = W_{gate(c)}h[k][unit(c)] as fp16
__global__ void pack_Wt(const float* __restrict__ Wgh, const float* __restrict__ Wih,
                        const float* __restrict__ Wfh, const float* __restrict__ Woh,
                        _Float16* __restrict__ Wt) {
  const int c = blockIdx.x;
  const int gate = c & 3, unit = c >> 2;
  const float* W = gate == 0 ? Wgh : gate == 1 ? Wih : gate == 2 ? Wfh : Woh;
  for (int k = threadIdx.x; k < 1024; k += 256)
    Wt[(size_t)c * 1024 + k] = (_Float16)W[k * 1024 + unit];
}

// ---------------- persistent LSTM: 8 independent row-groups of 16 batch rows.
// Block = (grp=blk&7, sub=blk>>3): 128 gate-cols, B in VGPRs. Per step, ONE
// __syncthreads:  [all waves] poll 8 wave-flags x 32 blocks >= t  ->  A-stage
// (sc0 sc1 direct-to-LLC, swizzled LDS)  ->  bar  ->  MFMA (acc init = exact-P)
// ->  IN-WAVE gates via quad shfl_xor (no pre[]-LDS)  ->  l15==0 lanes publish
// 8B sc1  ->  per-wave vmcnt(0) drain  ->  lane0 stores wave-flag[blk][wid]=t+1.
// flag[S][w]=t+1 certifies wave w of S passed bar(t) (so S finished reading
// h_t) AND drained its h_{t+1} slice to LLC. Consumer's poll(t+1) therefore
// certifies both data-ready and WAR-safety for the double buffer; it also
// subsumes the end-of-step intra-block barrier (own block's flags included).
__launch_bounds__(512, 2)
__global__ void lstm_step_all(const int* __restrict__ x,
                              const float* __restrict__ P,
                              const _Float16* __restrict__ Wt,
                              _Float16* __restrict__ hbuf,
                              float* __restrict__ h32,
                              const float* __restrict__ h_init,
                              const float* __restrict__ c_init,
                              unsigned int* __restrict__ flags) {
  cg::grid_group grid = cg::this_grid();
  __shared__ _Float16 alds[16 * 1024];   // 32 KB staged A (granule-XOR swizzled)
  __shared__ int xs2[2][16];
  const int tid = threadIdx.x;
  const int blk = blockIdx.x;
  const int grp = blk & 7;      // row-group
  const int sub = blk >> 3;     // 0..31 col-partition
  const int lane = tid & 63;
  const int wid = tid >> 6;
  const int l15 = lane & 15;
  const int gg = lane >> 4;
  const int kg = gg * 8;
  const int gt = l15 & 3;         // gate index within quad (0=g,1=i,2=f,3=o)
  const int colbase = sub * 128;  // gate-col base
  const int ubase = sub * 32;     // hidden-unit base
  const int rowbase = grp * 16;   // batch-row base

  if (tid < 8)
    __hip_atomic_store(&flags[blk * FLAG_STRIDE + tid], 0u, __ATOMIC_RELAXED,
                       __HIP_MEMORY_SCOPE_AGENT);

  // B resident in VGPRs: wave w covers cols colbase + w*16 .. +16, all K
  h8 bfr[32];
  {
    const _Float16* wp = Wt + (size_t)(colbase + wid * 16 + l15) * 1024 + kg;
#pragma unroll
    for (int s = 0; s < 32; s++) bfr[s] = *(const h8*)(wp + s * 32);
  }

  // init h0 slice (this block's 16 rows x 32 units) into buffer 0
  if (tid < 128) {
    int r16 = tid >> 3, q = tid & 7;
    union { _Float16 h[4]; ull_t u; } pk;
#pragma unroll
    for (int u = 0; u < 4; u++) pk.h[u] = (_Float16)h_init[ubase + q * 4 + u];
    *(ull_t*)&hbuf[(size_t)(rowbase + r16) * 1024 + ubase + q * 4] = pk.u;
  }
  if (tid < 16) xs2[0][tid] = x[(rowbase + tid) * 513];
  // persistent c-state: lane gt==2 of each quad owns c for (4 rows, unit wu);
  // init is row-independent so splat across the f4.
  const int wu = wid * 4 + (l15 >> 2);  // local unit 0..31
  f4 cst;
  {
    float c0 = c_init[ubase + wu];
    cst = (f4){c0, c0, c0, c0};
  }
  grid.sync();  // covers h0, flags, Wt/P reads

  for (int t = 0; t < T_STEPS; t++) {
    const _Float16* hc = hbuf + (t & 1) * (128 * 1024);
    _Float16* hn = hbuf + ((t + 1) & 1) * (128 * 1024);

    // exact-P gather for acc init (P immutable -> plain cacheable loads),
    // issued before the poll so LLC/L2 latency hides under the wait.
    float pv0, pv1, pv2, pv3;
    {
      const float* pp = P + colbase + wid * 16 + l15;
      pv0 = pp[(size_t)xs2[t & 1][gg * 4 + 0] * 4096];
      pv1 = pp[(size_t)xs2[t & 1][gg * 4 + 1] * 4096];
      pv2 = pp[(size_t)xs2[t & 1][gg * 4 + 2] * 4096];
      pv3 = pp[(size_t)xs2[t & 1][gg * 4 + 3] * 4096];
    }

    // ---- poll (ALL waves): lane j watches block grp+8*(j&31)'s 8 wave-flags
    {
      const int tgt = t;
      const unsigned* fp = &flags[(grp + 8 * (lane & 31)) * FLAG_STRIDE];
      for (;;) {
        i32x4 f0, f1;
        asm volatile(
            "global_load_dwordx4 %0, %2, off sc0 sc1\n\t"
            "global_load_dwordx4 %1, %2, off offset:16 sc0 sc1\n\t"
            "s_waitcnt vmcnt(0)"
            : "=v"(f0), "=v"(f1) : "v"(fp) : "memory");
        int m01 = min(min(f0[0], f0[1]), min(f0[2], f0[3]));
        int m23 = min(min(f1[0], f1[1]), min(f1[2], f1[3]));
        if (__ballot(min(m01, m23) >= tgt) == ~0ull) break;
        __builtin_amdgcn_s_sleep(1);
      }
    }

    // ---- A-stage: 16 rows x 2KB via direct-to-LLC loads, swizzled into LDS
    {
      i32x4 av[4];
#pragma unroll
      for (int r = 0; r < 4; r++) {
        int idx = r * 512 + tid;
        int ar = idx >> 7, g = idx & 127;
        const _Float16* p = &hc[(size_t)(rowbase + ar) * 1024 + g * 8];
        asm volatile("global_load_dwordx4 %0, %1, off sc0 sc1"
                     : "=v"(av[r]) : "v"(p) : "memory");
      }
      asm volatile("s_waitcnt vmcnt(0)" ::: "memory");
      __builtin_amdgcn_sched_barrier(0);
#pragma unroll
      for (int r = 0; r < 4; r++) {
        int idx = r * 512 + tid;
        int ar = idx >> 7, g = idx & 127;
        *(i32x4*)&alds[ar * 1024 + ((g ^ (ar & 7)) * 8)] = av[r];
      }
    }
    if (t + 1 < T_STEPS && tid < 16)
      xs2[(t + 1) & 1][tid] = x[(rowbase + tid) * 513 + (t + 1)];
    __syncthreads();  // the ONLY barrier: alds ready for all waves

    // ---- MFMA: 16 rows x 16 cols x K=1024; acc chain 0 inits with exact-P
    f4 ac0 = {pv0, pv1, pv2, pv3};
    f4 ac1 = {0.f, 0.f, 0.f, 0.f}, ac2 = ac1, ac3 = ac1;
#pragma unroll
    for (int s = 0; s < 32; s++) {
      int g = s * 4 + gg;
      h8 a = *(const h8*)&alds[l15 * 1024 + ((g ^ (l15 & 7)) * 8)];
      if ((s & 3) == 0) ac0 = __builtin_amdgcn_mfma_f32_16x16x32_f16(a, bfr[s], ac0, 0, 0, 0);
      else if ((s & 3) == 1) ac1 = __builtin_amdgcn_mfma_f32_16x16x32_f16(a, bfr[s], ac1, 0, 0, 0);
      else if ((s & 3) == 2) ac2 = __builtin_amdgcn_mfma_f32_16x16x32_f16(a, bfr[s], ac2, 0, 0, 0);
      else ac3 = __builtin_amdgcn_mfma_f32_16x16x32_f16(a, bfr[s], ac3, 0, 0, 0);
    }
    f4 v = (ac0 + ac1) + (ac2 + ac3);  // pre-activation: rows gg*4..+4, col w*16+l15

    // ---- in-wave gates via quad shfl_xor (quad lanes 4u..4u+3 = g,i,f,o of unit u)
    f4 w;
#pragma unroll
    for (int i = 0; i < 4; i++) w[i] = (gt == 0) ? tanh_fast(v[i]) : sigm(v[i]);
    f4 wx1 = shfl_xor4(w, 1);
    f4 prod = w * wx1;              // on gt0: tanh(g)*sigm(i)
    f4 cf = cst * w;                // on gt2: c*sigm(f)
    f4 cfx = shfl_xor4(cf, 2);      // gt0 receives c*f
    f4 cn = prod + cfx;             // valid on gt0
    f4 cnx = shfl_xor4(cn, 2);      // gt2 receives new c
#pragma unroll
    for (int i = 0; i < 4; i++) cst[i] = (gt == 2) ? cnx[i] : cst[i];
    f4 ov = shfl_xor4(w, 3);        // gt0 receives sigm(o)
    f4 h;
#pragma unroll
    for (int i = 0; i < 4; i++) h[i] = tanh_fast(cn[i]) * ov[i];  // valid on gt0

    if (t == T_STEPS - 1) {
      if (gt == 0) {
#pragma unroll
        for (int i = 0; i < 4; i++)
          h32[(size_t)(rowbase + gg * 4 + i) * 1024 + ubase + wu] = h[i];
      }
      break;
    }

    // ---- publish: pack 4 units (quad leaders l15=0,4,8,12) into 8B, store sc1
    {
      unsigned u16[4], a32[4], b32[4];
#pragma unroll
      for (int i = 0; i < 4; i++) {
        union { _Float16 hh; unsigned short us; } cv;
        cv.hh = (_Float16)h[i];
        u16[i] = cv.us;
      }
#pragma unroll
      for (int i = 0; i < 4; i++) {
        a32[i] = u16[i] | ((unsigned)__shfl_down((int)u16[i], 4, 64) << 16);
        b32[i] = (unsigned)__shfl_down((int)a32[i], 8, 64);
      }
      if (l15 == 0) {
#pragma unroll
        for (int i = 0; i < 4; i++) {
          ull_t pv8 = (ull_t)a32[i] | ((ull_t)b32[i] << 32);
          __hip_atomic_store(
              (ull_t*)&hn[(size_t)(rowbase + gg * 4 + i) * 1024 + ubase + wid * 4],
              pv8, __ATOMIC_RELAXED, __HIP_MEMORY_SCOPE_AGENT);
        }
      }
    }
    // per-wave drain: this wave's h-slice ack'd at LLC, then publish wave-flag
    asm volatile("s_waitcnt vmcnt(0)" ::: "memory");
    if (lane == 0)
      __hip_atomic_store(&flags[blk * FLAG_STRIDE + wid], (unsigned)(t + 1),
                         __ATOMIC_RELAXED, __HIP_MEMORY_SCOPE_AGENT);
  }
}

// ---------------- final projection p = h_T @ W_ph + b_p (fp32)
__global__ void proj(const float* __restrict__ h32, const float* __restrict__ Wph,
                     const float* __restrict__ bp, float* __restrict__ logits) {
  const int b = blockIdx.x >> 1;
  const int cc = (blockIdx.x & 1) * 256 + threadIdx.x;
  const float* hrow = h32 + b * 1024;
  float acc = bp[cc];
#pragma unroll 4
  for (int k = 0; k < 1024; k++) acc += hrow[k] * Wph[k * 512 + cc];
  logits[b * 512 + cc] = acc;
}

// ---------------- row-wise log_softmax
__global__ void lsm(const float* __restrict__ logits, float* __restrict__ out) {
  const int b = blockIdx.x;
  const int tid = threadIdx.x;
  __shared__ float sm[4];
  __shared__ float se[4];
  float v0 = logits[b * 512 + tid];
  float v1 = logits[b * 512 + 256 + tid];
  float m = fmaxf(v0, v1);
  for (int o = 1; o < 64; o <<= 1) m = fmaxf(m, __shfl_xor(m, o, 64));
  if ((tid & 63) == 0) sm[tid >> 6] = m;
  __syncthreads();
  m = fmaxf(fmaxf(sm[0], sm[1]), fmaxf(sm[2], sm[3]));
  float e = expf(v0 - m) + expf(v1 - m);
  for (int o = 1; o < 64; o <<= 1) e += __shfl_xor(e, o, 64);
  if ((tid & 63) == 0) se[tid >> 6] = e;
  __syncthreads();
  float ls = logf(se[0] + se[1] + se[2] + se[3]) + m;
  out[b * 512 + tid] = v0 - ls;
  out[b * 512 + 256 + tid] = v1 - ls;
}

extern "C" void kernel_launch(void* const* d_in, const int* in_sizes, int n_in,
                              void* d_out, int out_size, void* d_ws, size_t ws_size,
                              hipStream_t stream) {
  const int* x = (const int*)d_in[0];
  const float* emb = (const float*)d_in[1];
  const float* Wgx = (const float*)d_in[2];
  const float* Wgh = (const float*)d_in[3];
  const float* bg = (const float*)d_in[4];
  const float* Wix = (const float*)d_in[5];
  const float* Wih = (const float*)d_in[6];
  const float* bi = (const float*)d_in[7];
  const float* Wfx = (const float*)d_in[8];
  const float* Wfh = (const float*)d_in[9];
  const float* bf = (const float*)d_in[10];
  const float* Wox = (const float*)d_in[11];
  const float* Woh = (const float*)d_in[12];
  const float* bo = (const float*)d_in[13];
  const float* Wph = (const float*)d_in[14];
  const float* bp = (const float*)d_in[15];
  const float* h_init = (const float*)d_in[16];
  const float* c_init = (const float*)d_in[17];

  char* ws = (char*)d_ws;
  float* P = (float*)ws;                                   // 520*4096*4   = 8,519,680
  unsigned int* flags = (unsigned int*)(ws + (size_t)513 * 4096 * 4);  // 16 KB (P pad)
  _Float16* Wt = (_Float16*)(ws + 8519680);                // 4096*1024*2  = 8,388,608
  _Float16* hbuf = (_Float16*)(ws + 8519680 + 8388608);    // 2*128*1024*2 = 524,288
  float* h32 = (float*)(ws + 8519680 + 8388608 + 524288);  // 128*1024*4   = 524,288
  float* logits = (float*)(ws + 8519680 + 8388608 + 524288 + 524288);  // 128*512*4

  pack_P<<<dim3(65, 16), 256, 0, stream>>>(emb, Wgx, Wix, Wfx, Wox, bg, bi, bf, bo, P);
  pack_Wt<<<4096, 256, 0, stream>>>(Wgh, Wih, Wfh, Woh, Wt);

  void* args[] = {(void*)&x, (void*)&P, (void*)&Wt, (void*)&hbuf,
                  (void*)&h32, (void*)&h_init, (void*)&c_init, (void*)&flags};
  hipLaunchCooperativeKernel((void*)lstm_step_all, dim3(NBLK), dim3(512), args, 0, stream);

  proj<<<256, 256, 0, stream>>>(h32, Wph, bp, logits);
  lsm<<<128, 256, 0, stream>>>(logits, (float*)d_out);
}

// Round 13
// 2119.374 us; speedup vs baseline: 1.8897x; 1.8897x over previous
//
#include <hip/hip_runtime.h>
#include <hip/hip_cooperative_groups.h>
#include <cmath>

namespace cg = cooperative_groups;

#define T_STEPS 512
#define NBLK 256
#define FLAG_STRIDE 16  // 64B-padded flag lines, one flag per block

typedef _Float16 h8 __attribute__((ext_vector_type(8)));
typedef float f4 __attribute__((ext_vector_type(4)));
typedef int i32x4 __attribute__((ext_vector_type(4)));
typedef unsigned long long ull_t;

__device__ __forceinline__ float sigm(float v) { return 1.f / (1.f + __expf(-v)); }
__device__ __forceinline__ float tanh_fast(float v) { return 1.f - 2.f / (__expf(2.f * v) + 1.f); }

// ---------------- pack P = emb @ [Wx interleaved] + bias : [513][4096] fp32 (exact input path)
__global__ void pack_P(const float* __restrict__ emb,
                       const float* __restrict__ Wgx, const float* __restrict__ Wix,
                       const float* __restrict__ Wfx, const float* __restrict__ Wox,
                       const float* __restrict__ bg, const float* __restrict__ bi,
                       const float* __restrict__ bf_, const float* __restrict__ bo,
                       float* __restrict__ P) {
  __shared__ float es[8][512];
  const int vg = blockIdx.x;   // 0..64
  const int st = blockIdx.y;   // 0..15
  const int tid = threadIdx.x;
  for (int i = tid; i < 8 * 512; i += 256) {
    int vv = i >> 9, k = i & 511;
    int v = vg * 8 + vv;
    es[vv][k] = (v < 513) ? emb[v * 512 + k] : 0.f;
  }
  __syncthreads();
  const int c = st * 256 + tid;
  const int gate = c & 3, unit = c >> 2;
  const float* W = gate == 0 ? Wgx : gate == 1 ? Wix : gate == 2 ? Wfx : Wox;
  const float* bias = gate == 0 ? bg : gate == 1 ? bi : gate == 2 ? bf_ : bo;
  float acc[8];
  const float bv = bias[unit];
#pragma unroll
  for (int vv = 0; vv < 8; vv++) acc[vv] = bv;
  for (int k = 0; k < 512; k++) {
    float w = W[k * 1024 + unit];
#pragma unroll
    for (int vv = 0; vv < 8; vv++) acc[vv] += es[vv][k] * w;
  }
#pragma unroll
  for (int vv = 0; vv < 8; vv++) {
    int v = vg * 8 + vv;
    if (v < 513) P[(size_t)v * 4096 + c] = acc[vv];
  }
}

// ---------------- pack Wt[c][k] = W_{gate(c)}h[k][unit(c)] as fp16
__global__ void pack_Wt(const float* __restrict__ Wgh, const float* __restrict__ Wih,
                        const float* __restrict__ Wfh, const float* __restrict__ Woh,
                        _Float16* __restrict__ Wt) {
  const int c = blockIdx.x;
  const int gate = c & 3, unit = c >> 2;
  const float* W = gate == 0 ? Wgh : gate == 1 ? Wih : gate == 2 ? Wfh : Woh;
  for (int k = threadIdx.x; k < 1024; k += 256)
    Wt[(size_t)c * 1024 + k] = (_Float16)W[k * 1024 + unit];
}

// ---------------- persistent LSTM: 8 independent row-groups of 16 batch rows.
// R11 structure with 2 barriers/step instead of 4:
//   [each wave] poll 32 per-block flags >= t  ->  stage own alds share (sc0 sc1)
//   -> BAR1 -> MFMA -> pre[] scatter -> BAR2 -> gates + shfl-pack publish
//   -> per-wave vmcnt(0) drain -> lane0 ds_add; last wave stores block flag=t+1.
// Ordering safety with only 2 barriers:
//  * alds(t+1) writes happen after BAR... every wave's path to staging(t+1)
//    passes BAR2(t), and every wave's alds(t) reads (MFMA) precede its BAR2(t)
//    arrival  => no alds WAR race.
//  * pre(t+1) scatter happens after BAR1(t+1); every wave's pre(t) reads
//    (gates) precede its BAR1(t+1) arrival  => no pre WAR race.
//  * flag=t+1 is stored only after ALL 8 waves vmcnt-drained their h publishes
//    (LDS counter reaches 8t+8) => consumers' poll certifies data at LLC, and
//    (as in R11) flag >= t also certifies h_{t-1} readers done => WAR-safe
//    double buffer.
__launch_bounds__(512, 2)
__global__ void lstm_step_all(const int* __restrict__ x,
                              const float* __restrict__ P,
                              const _Float16* __restrict__ Wt,
                              _Float16* __restrict__ hbuf,
                              float* __restrict__ h32,
                              const float* __restrict__ h_init,
                              const float* __restrict__ c_init,
                              unsigned int* __restrict__ flags) {
  cg::grid_group grid = cg::this_grid();
  __shared__ _Float16 alds[16 * 1024];   // 32 KB staged A (granule-XOR swizzled)
  __shared__ float pre[16 * 132];        // 8.25 KB fp32 pre-activations
  __shared__ unsigned scnt;              // monotone per-step wave-completion counter
  const int tid = threadIdx.x;
  const int blk = blockIdx.x;
  const int grp = blk & 7;      // row-group
  const int sub = blk >> 3;     // 0..31 col-partition
  const int lane = tid & 63;
  const int wid = tid >> 6;
  const int l15 = lane & 15;
  const int gg = lane >> 4;
  const int kg = gg * 8;
  const int colbase = sub * 128;  // gate-col base
  const int ubase = sub * 32;     // hidden-unit base
  const int rowbase = grp * 16;   // batch-row base

  if (tid == 0) {
    scnt = 0u;
    __hip_atomic_store(&flags[blk * FLAG_STRIDE], 0u, __ATOMIC_RELAXED,
                       __HIP_MEMORY_SCOPE_AGENT);
  }

  // B resident in VGPRs: wave w covers cols colbase + w*16 .. +16, all K
  h8 bfr[32];
  {
    const _Float16* wp = Wt + (size_t)(colbase + wid * 16 + l15) * 1024 + kg;
#pragma unroll
    for (int s = 0; s < 32; s++) bfr[s] = *(const h8*)(wp + s * 32);
  }

  // init h0 slice (this block's 16 rows x 32 units) into buffer 0
  if (tid < 128) {
    int r16 = tid >> 3, q = tid & 7;
    union { _Float16 h[4]; ull_t u; } pk;
#pragma unroll
    for (int u = 0; u < 4; u++) pk.h[u] = (_Float16)h_init[ubase + q * 4 + u];
    *(ull_t*)&hbuf[(size_t)(rowbase + r16) * 1024 + ubase + q * 4] = pk.u;
  }
  // gate-phase identity: row = tid>>5, unit = tid&31 (persistent c state)
  const int grow = tid >> 5;
  const int gu = tid & 31;
  float cst = c_init[ubase + gu];
  grid.sync();  // covers h0, flags, scnt, Wt/P reads

  for (int t = 0; t < T_STEPS; t++) {
    const _Float16* hc = hbuf + (t & 1) * (128 * 1024);
    _Float16* hn = hbuf + ((t + 1) & 1) * (128 * 1024);

    // exact-P gather issued early (x then P, both cache-warm plain loads);
    // latency hides under the poll + A-stage window
    const int xv = x[(rowbase + grow) * 513 + t];
    const float* prow = P + (size_t)xv * 4096 + colbase + gu * 4;
    f4 pv = *(const f4*)prow;

    // ---- poll (EACH wave independently): lanes 0..31 watch the 32 block flags
    {
      const unsigned tgt = (unsigned)t;
      const unsigned* fp = &flags[(grp + 8 * (lane & 31)) * FLAG_STRIDE];
      for (;;) {
        unsigned f = tgt;
        if (lane < 32) {
          asm volatile("global_load_dword %0, %1, off sc0 sc1\n\ts_waitcnt vmcnt(0)"
                       : "=v"(f) : "v"(fp) : "memory");
        }
        if (__ballot(f >= tgt) == ~0ull) break;
        __builtin_amdgcn_s_sleep(1);
      }
    }

    // ---- A-stage: this thread's share of 16 rows x 2KB via direct-to-LLC loads
    {
      i32x4 av[4];
#pragma unroll
      for (int r = 0; r < 4; r++) {
        int idx = r * 512 + tid;
        int ar = idx >> 7, g = idx & 127;
        const _Float16* p = &hc[(size_t)(rowbase + ar) * 1024 + g * 8];
        asm volatile("global_load_dwordx4 %0, %1, off sc0 sc1"
                     : "=v"(av[r]) : "v"(p) : "memory");
      }
      asm volatile("s_waitcnt vmcnt(0)" ::: "memory");
      __builtin_amdgcn_sched_barrier(0);
#pragma unroll
      for (int r = 0; r < 4; r++) {
        int idx = r * 512 + tid;
        int ar = idx >> 7, g = idx & 127;
        *(i32x4*)&alds[ar * 1024 + ((g ^ (ar & 7)) * 8)] = av[r];
      }
    }
    __syncthreads();  // BAR1: alds ready (and pre[] of step t-1 fully consumed)

    // ---- MFMA: 16 rows x 16 cols x K=1024, B from regs, 4 acc chains
    f4 ac0 = {0.f, 0.f, 0.f, 0.f}, ac1 = ac0, ac2 = ac0, ac3 = ac0;
#pragma unroll
    for (int s = 0; s < 32; s++) {
      int g = s * 4 + gg;
      h8 a = *(const h8*)&alds[l15 * 1024 + ((g ^ (l15 & 7)) * 8)];
      if ((s & 3) == 0) ac0 = __builtin_amdgcn_mfma_f32_16x16x32_f16(a, bfr[s], ac0, 0, 0, 0);
      else if ((s & 3) == 1) ac1 = __builtin_amdgcn_mfma_f32_16x16x32_f16(a, bfr[s], ac1, 0, 0, 0);
      else if ((s & 3) == 2) ac2 = __builtin_amdgcn_mfma_f32_16x16x32_f16(a, bfr[s], ac2, 0, 0, 0);
      else ac3 = __builtin_amdgcn_mfma_f32_16x16x32_f16(a, bfr[s], ac3, 0, 0, 0);
    }
    f4 acc = (ac0 + ac1) + (ac2 + ac3);
#pragma unroll
    for (int i = 0; i < 4; i++)
      pre[(gg * 4 + i) * 132 + wid * 16 + l15] = acc[i];
    __syncthreads();  // BAR2: pre ready (and alds of step t fully consumed)

    // ---- gates: all 512 threads (16 rows x 32 units); shfl-pack h and
    // publish 8B per 4-lane leader directly
    {
      f4 q = *(const f4*)&pre[grow * 132 + gu * 4];
      q += pv;
      float g_ = tanh_fast(q[0]);
      float i_ = sigm(q[1]);
      float f_ = sigm(q[2]);
      float o_ = sigm(q[3]);
      cst = g_ * i_ + cst * f_;
      float hv = tanh_fast(cst) * o_;
      if (t == T_STEPS - 1) {
        h32[(size_t)(rowbase + grow) * 1024 + ubase + gu] = hv;
      } else {
        union { _Float16 hh; unsigned short us; } cv;
        cv.hh = (_Float16)hv;
        unsigned v0 = cv.us;
        unsigned v1 = (unsigned)__shfl_down((int)v0, 1);
        unsigned lo = (v0 & 0xffffu) | (v1 << 16);
        unsigned lo2 = (unsigned)__shfl_down((int)lo, 2);
        if ((gu & 3) == 0) {
          ull_t pv8 = (ull_t)lo | ((ull_t)lo2 << 32);
          __hip_atomic_store((ull_t*)&hn[(size_t)(rowbase + grow) * 1024 + ubase + gu],
                             pv8, __ATOMIC_RELAXED, __HIP_MEMORY_SCOPE_AGENT);
        }
      }
    }
    if (t == T_STEPS - 1) break;

    // ---- per-wave drain + last-wave flag publish (no block barrier)
    asm volatile("s_waitcnt vmcnt(0)" ::: "memory");  // this wave's h stores at LLC
    if (lane == 0) {
      unsigned ret = atomicAdd(&scnt, 1u);  // LDS, monotone across steps
      if (ret == 8u * (unsigned)t + 7u)     // last of this step's 8 waves
        __hip_atomic_store(&flags[blk * FLAG_STRIDE], (unsigned)(t + 1),
                           __ATOMIC_RELAXED, __HIP_MEMORY_SCOPE_AGENT);
    }
  }
}

// ---------------- final projection p = h_T @ W_ph + b_p (fp32)
__global__ void proj(const float* __restrict__ h32, const float* __restrict__ Wph,
                     const float* __restrict__ bp, float* __restrict__ logits) {
  const int b = blockIdx.x >> 1;
  const int cc = (blockIdx.x & 1) * 256 + threadIdx.x;
  const float* hrow = h32 + b * 1024;
  float acc = bp[cc];
#pragma unroll 4
  for (int k = 0; k < 1024; k++) acc += hrow[k] * Wph[k * 512 + cc];
  logits[b * 512 + cc] = acc;
}

// ---------------- row-wise log_softmax
__global__ void lsm(const float* __restrict__ logits, float* __restrict__ out) {
  const int b = blockIdx.x;
  const int tid = threadIdx.x;
  __shared__ float sm[4];
  __shared__ float se[4];
  float v0 = logits[b * 512 + tid];
  float v1 = logits[b * 512 + 256 + tid];
  float m = fmaxf(v0, v1);
  for (int o = 1; o < 64; o <<= 1) m = fmaxf(m, __shfl_xor(m, o, 64));
  if ((tid & 63) == 0) sm[tid >> 6] = m;
  __syncthreads();
  m = fmaxf(fmaxf(sm[0], sm[1]), fmaxf(sm[2], sm[3]));
  float e = expf(v0 - m) + expf(v1 - m);
  for (int o = 1; o < 64; o <<= 1) e += __shfl_xor(e, o, 64);
  if ((tid & 63) == 0) se[tid >> 6] = e;
  __syncthreads();
  float ls = logf(se[0] + se[1] + se[2] + se[3]) + m;
  out[b * 512 + tid] = v0 - ls;
  out[b * 512 + 256 + tid] = v1 - ls;
}

extern "C" void kernel_launch(void* const* d_in, const int* in_sizes, int n_in,
                              void* d_out, int out_size, void* d_ws, size_t ws_size,
                              hipStream_t stream) {
  const int* x = (const int*)d_in[0];
  const float* emb = (const float*)d_in[1];
  const float* Wgx = (const float*)d_in[2];
  const float* Wgh = (const float*)d_in[3];
  const float* bg = (const float*)d_in[4];
  const float* Wix = (const float*)d_in[5];
  const float* Wih = (const float*)d_in[6];
  const float* bi = (const float*)d_in[7];
  const float* Wfx = (const float*)d_in[8];
  const float* Wfh = (const float*)d_in[9];
  const float* bf = (const float*)d_in[10];
  const float* Wox = (const float*)d_in[11];
  const float* Woh = (const float*)d_in[12];
  const float* bo = (const float*)d_in[13];
  const float* Wph = (const float*)d_in[14];
  const float* bp = (const float*)d_in[15];
  const float* h_init = (const float*)d_in[16];
  const float* c_init = (const float*)d_in[17];

  char* ws = (char*)d_ws;
  float* P = (float*)ws;                                   // 520*4096*4   = 8,519,680
  unsigned int* flags = (unsigned int*)(ws + (size_t)513 * 4096 * 4);  // 16 KB (P pad)
  _Float16* Wt = (_Float16*)(ws + 8519680);                // 4096*1024*2  = 8,388,608
  _Float16* hbuf = (_Float16*)(ws + 8519680 + 8388608);    // 2*128*1024*2 = 524,288
  float* h32 = (float*)(ws + 8519680 + 8388608 + 524288);  // 128*1024*4   = 524,288
  float* logits = (float*)(ws + 8519680 + 8388608 + 524288 + 524288);  // 128*512*4

  pack_P<<<dim3(65, 16), 256, 0, stream>>>(emb, Wgx, Wix, Wfx, Wox, bg, bi, bf, bo, P);
  pack_Wt<<<4096, 256, 0, stream>>>(Wgh, Wih, Wfh, Woh, Wt);

  void* args[] = {(void*)&x, (void*)&P, (void*)&Wt, (void*)&hbuf,
                  (void*)&h32, (void*)&h_init, (void*)&c_init, (void*)&flags};
  hipLaunchCooperativeKernel((void*)lstm_step_all, dim3(NBLK), dim3(512), args, 0, stream);

  proj<<<256, 256, 0, stream>>>(h32, Wph, bp, logits);
  lsm<<<128, 256, 0, stream>>>(logits, (float*)d_out);
}

// Round 15
// 2074.101 us; speedup vs baseline: 1.9309x; 1.0218x over previous
//
#include <hip/hip_runtime.h>
#include <hip/hip_cooperative_groups.h>
#include <cmath>

namespace cg = cooperative_groups;

#define T_STEPS 512
#define NBLK 256
#define FLAG_STRIDE 16  // 64B-padded flag lines, one flag per block

typedef _Float16 h8 __attribute__((ext_vector_type(8)));
typedef float f4 __attribute__((ext_vector_type(4)));
typedef int i32x4 __attribute__((ext_vector_type(4)));
typedef unsigned long long ull_t;

__device__ __forceinline__ float sigm(float v) { return 1.f / (1.f + __expf(-v)); }
__device__ __forceinline__ float tanh_fast(float v) { return 1.f - 2.f / (__expf(2.f * v) + 1.f); }

// raw workgroup barrier with compiler memory fences but NO counter drain
__device__ __forceinline__ void barrier_raw() {
  __builtin_amdgcn_sched_barrier(0);
  asm volatile("" ::: "memory");
  __builtin_amdgcn_s_barrier();
  asm volatile("" ::: "memory");
  __builtin_amdgcn_sched_barrier(0);
}

// ---------------- pack P = emb @ [Wx interleaved] + bias : [513][4096] fp32 (exact input path)
__global__ void pack_P(const float* __restrict__ emb,
                       const float* __restrict__ Wgx, const float* __restrict__ Wix,
                       const float* __restrict__ Wfx, const float* __restrict__ Wox,
                       const float* __restrict__ bg, const float* __restrict__ bi,
                       const float* __restrict__ bf_, const float* __restrict__ bo,
                       float* __restrict__ P) {
  __shared__ float es[8][512];
  const int vg = blockIdx.x;   // 0..64
  const int st = blockIdx.y;   // 0..15
  const int tid = threadIdx.x;
  for (int i = tid; i < 8 * 512; i += 256) {
    int vv = i >> 9, k = i & 511;
    int v = vg * 8 + vv;
    es[vv][k] = (v < 513) ? emb[v * 512 + k] : 0.f;
  }
  __syncthreads();
  const int c = st * 256 + tid;
  const int gate = c & 3, unit = c >> 2;
  const float* W = gate == 0 ? Wgx : gate == 1 ? Wix : gate == 2 ? Wfx : Wox;
  const float* bias = gate == 0 ? bg : gate == 1 ? bi : gate == 2 ? bf_ : bo;
  float acc[8];
  const float bv = bias[unit];
#pragma unroll
  for (int vv = 0; vv < 8; vv++) acc[vv] = bv;
  for (int k = 0; k < 512; k++) {
    float w = W[k * 1024 + unit];
#pragma unroll
    for (int vv = 0; vv < 8; vv++) acc[vv] += es[vv][k] * w;
  }
#pragma unroll
  for (int vv = 0; vv < 8; vv++) {
    int v = vg * 8 + vv;
    if (v < 513) P[(size_t)v * 4096 + c] = acc[vv];
  }
}

// ---------------- pack Wt[c][k] = W_{gate(c)}h[k][unit(c)] as fp16
__global__ void pack_Wt(const float* __restrict__ Wgh, const float* __restrict__ Wih,
                        const float* __restrict__ Wfh, const float* __restrict__ Woh,
                        _Float16* __restrict__ Wt) {
  const int c = blockIdx.x;
  const int gate = c & 3, unit = c >> 2;
  const float* W = gate == 0 ? Wgh : gate == 1 ? Wih : gate == 2 ? Wfh : Woh;
  for (int k = threadIdx.x; k < 1024; k += 256)
    Wt[(size_t)c * 1024 + k] = (_Float16)W[k * 1024 + unit];
}

// ---------------- persistent LSTM: 8 independent row-groups of 16 batch rows.
// R11 protocol skeleton (wave0-only poll, per-block flag, sc1 publishes) with a
// counted-vmcnt split-K pipeline and last-wave flag publish:
//   [top] x/P gather issued -> wave0 polls 32 flags >= t -> BAR_p (raw)
//   -> issue 4 A-loads -> vmcnt(2) -> write K-lo LDS -> lgkmcnt(0) -> BAR_a
//   -> MFMA s=0..15 (K-hi loads still in flight) -> vmcnt(0) -> write K-hi
//   -> lgkmcnt(0) -> BAR_b -> MFMA s=16..31 -> pre scatter -> lgkmcnt(0)
//   -> BAR_c -> gates + shfl-pack sc1 publish -> per-wave vmcnt(0) drain
//   -> lane0 LDS atomicAdd; wave seeing ret==8t+7 stores flag=t+1 (sc1).
// Staging layout (FIXED vs R14): thread covers row arow=tid>>5, granules
// agb+{0,32,64,96} (16B granules, agb=tid&31). Global byte offsets are
// r*512 B; LDS element offsets are r*256 fp16 (32 granules x 8 fp16).
// Ordering safety:
//  * alds WAR: stage(t+1) writes follow BAR_p(t+1); every wave's MFMA reads of
//    alds(t) precede its BAR_p(t+1) arrival (program order through BAR_c(t)).
//  * pre WAR: scatter(t+1) follows BAR_b(t+1) > BAR_p(t+1); gates reads of
//    pre(t) precede BAR_p(t+1) arrival.
//  * flag=t+1 stored only after all 8 waves vmcnt(0)-drained their h publishes
//    (LDS counter reaches 8t+8) => consumers' poll certifies data at LLC.
//    flag >= t also certifies this block finished reading h_{t-1} => WAR-safe
//    double buffer.
//  * vmcnt(2) correctness: outstanding at that point = {xv, pv, av0..av3}
//    in issue order (plain loads cannot cross the "memory" asm); waiting to 2
//    retires xv, pv, av0, av1 — exactly what the K-lo writes consume.
__launch_bounds__(512, 2)
__global__ void lstm_step_all(const int* __restrict__ x,
                              const float* __restrict__ P,
                              const _Float16* __restrict__ Wt,
                              _Float16* __restrict__ hbuf,
                              float* __restrict__ h32,
                              const float* __restrict__ h_init,
                              const float* __restrict__ c_init,
                              unsigned int* __restrict__ flags) {
  cg::grid_group grid = cg::this_grid();
  __shared__ _Float16 alds[16 * 1024];   // 32 KB staged A (granule-XOR swizzled)
  __shared__ float pre[16 * 132];        // 8.25 KB fp32 pre-activations
  __shared__ unsigned scnt;              // monotone per-step wave-completion counter
  const int tid = threadIdx.x;
  const int blk = blockIdx.x;
  const int grp = blk & 7;      // row-group
  const int sub = blk >> 3;     // 0..31 col-partition
  const int lane = tid & 63;
  const int wid = tid >> 6;
  const int l15 = lane & 15;
  const int gg = lane >> 4;
  const int kg = gg * 8;
  const int colbase = sub * 128;  // gate-col base
  const int ubase = sub * 32;     // hidden-unit base
  const int rowbase = grp * 16;   // batch-row base
  const int arow = tid >> 5;      // staging row (0..15), 32 threads per row
  const int agb = tid & 31;       // staging granule base (of 128, 16B granules)

  if (tid == 0) {
    scnt = 0u;
    __hip_atomic_store(&flags[blk * FLAG_STRIDE], 0u, __ATOMIC_RELAXED,
                       __HIP_MEMORY_SCOPE_AGENT);
  }

  // B resident in VGPRs: wave w covers cols colbase + w*16 .. +16, all K
  h8 bfr[32];
  {
    const _Float16* wp = Wt + (size_t)(colbase + wid * 16 + l15) * 1024 + kg;
#pragma unroll
    for (int s = 0; s < 32; s++) bfr[s] = *(const h8*)(wp + s * 32);
  }

  // init h0 slice (this block's 16 rows x 32 units) into buffer 0
  if (tid < 128) {
    int r16 = tid >> 3, q = tid & 7;
    union { _Float16 h[4]; ull_t u; } pk;
#pragma unroll
    for (int u = 0; u < 4; u++) pk.h[u] = (_Float16)h_init[ubase + q * 4 + u];
    *(ull_t*)&hbuf[(size_t)(rowbase + r16) * 1024 + ubase + q * 4] = pk.u;
  }
  // gate-phase identity: row = tid>>5, unit = tid&31 (persistent c state)
  const int grow = tid >> 5;
  const int gu = tid & 31;
  float cst = c_init[ubase + gu];
  // swizzled LDS base for staging writes (granule XOR on low 3 bits)
  const int abase = arow * 1024 + ((agb ^ (arow & 7)) * 8);
  grid.sync();  // covers h0, flags, scnt, Wt/P reads

  for (int t = 0; t < T_STEPS; t++) {
    const _Float16* hc = hbuf + (t & 1) * (128 * 1024);
    _Float16* hn = hbuf + ((t + 1) & 1) * (128 * 1024);

    // exact-P gather issued early (x then P, cache-warm plain loads);
    // latency hides under poll + stage + MFMA (consumed in gates)
    const int xv = x[(rowbase + grow) * 513 + t];
    const float* prow = P + (size_t)xv * 4096 + colbase + gu * 4;
    f4 pv = *(const f4*)prow;

    // ---- poll (wave0 only): lanes 0..31 watch the group's 32 block flags
    if (tid < 64) {
      const unsigned tgt = (unsigned)t;
      const unsigned* fp = &flags[(grp + 8 * (lane & 31)) * FLAG_STRIDE];
      for (;;) {
        unsigned f = tgt;
        if (lane < 32) {
          asm volatile("global_load_dword %0, %1, off sc0 sc1\n\ts_waitcnt vmcnt(0)"
                       : "=v"(f) : "v"(fp) : "memory");
        }
        if (__ballot(f >= tgt) == ~0ull) break;
        __builtin_amdgcn_s_sleep(1);
      }
    }
    barrier_raw();  // BAR_p: h_t certified; pv loads may remain in flight

    // ---- A-stage, split-K: issue all 4 direct-to-LLC loads (K-lo first)
    i32x4 av0, av1, av2, av3;
    {
      const _Float16* pbase = &hc[(size_t)(rowbase + arow) * 1024 + agb * 8];
      asm volatile("global_load_dwordx4 %0, %1, off sc0 sc1"
                   : "=v"(av0) : "v"(pbase) : "memory");
      asm volatile("global_load_dwordx4 %0, %1, off offset:512 sc0 sc1"
                   : "=v"(av1) : "v"(pbase) : "memory");
      asm volatile("global_load_dwordx4 %0, %1, off offset:1024 sc0 sc1"
                   : "=v"(av2) : "v"(pbase) : "memory");
      asm volatile("global_load_dwordx4 %0, %1, off offset:1536 sc0 sc1"
                   : "=v"(av3) : "v"(pbase) : "memory");
    }
    // wait K-lo only: retires xv, pv, av0, av1 (in-order retirement)
    asm volatile("s_waitcnt vmcnt(2)" ::: "memory");
    __builtin_amdgcn_sched_barrier(0);
    *(i32x4*)&alds[abase] = av0;
    *(i32x4*)&alds[abase + 256] = av1;  // +32 granules = +256 fp16
    asm volatile("s_waitcnt lgkmcnt(0)" ::: "memory");
    barrier_raw();  // BAR_a: K-lo LDS ready; K-hi loads still flying

    // ---- MFMA on K-lo (s = 0..15) while K-hi completes
    f4 ac0 = {0.f, 0.f, 0.f, 0.f}, ac1 = ac0, ac2 = ac0, ac3 = ac0;
#pragma unroll
    for (int s = 0; s < 16; s++) {
      int g = s * 4 + gg;
      h8 a = *(const h8*)&alds[l15 * 1024 + ((g ^ (l15 & 7)) * 8)];
      if ((s & 3) == 0) ac0 = __builtin_amdgcn_mfma_f32_16x16x32_f16(a, bfr[s], ac0, 0, 0, 0);
      else if ((s & 3) == 1) ac1 = __builtin_amdgcn_mfma_f32_16x16x32_f16(a, bfr[s], ac1, 0, 0, 0);
      else if ((s & 3) == 2) ac2 = __builtin_amdgcn_mfma_f32_16x16x32_f16(a, bfr[s], ac2, 0, 0, 0);
      else ac3 = __builtin_amdgcn_mfma_f32_16x16x32_f16(a, bfr[s], ac3, 0, 0, 0);
    }
    asm volatile("s_waitcnt vmcnt(0)" ::: "memory");
    __builtin_amdgcn_sched_barrier(0);
    *(i32x4*)&alds[abase + 512] = av2;  // +64 granules = +512 fp16
    *(i32x4*)&alds[abase + 768] = av3;  // +96 granules = +768 fp16
    asm volatile("s_waitcnt lgkmcnt(0)" ::: "memory");
    barrier_raw();  // BAR_b: K-hi LDS ready

    // ---- MFMA on K-hi (s = 16..31)
#pragma unroll
    for (int s = 16; s < 32; s++) {
      int g = s * 4 + gg;
      h8 a = *(const h8*)&alds[l15 * 1024 + ((g ^ (l15 & 7)) * 8)];
      if ((s & 3) == 0) ac0 = __builtin_amdgcn_mfma_f32_16x16x32_f16(a, bfr[s], ac0, 0, 0, 0);
      else if ((s & 3) == 1) ac1 = __builtin_amdgcn_mfma_f32_16x16x32_f16(a, bfr[s], ac1, 0, 0, 0);
      else if ((s & 3) == 2) ac2 = __builtin_amdgcn_mfma_f32_16x16x32_f16(a, bfr[s], ac2, 0, 0, 0);
      else ac3 = __builtin_amdgcn_mfma_f32_16x16x32_f16(a, bfr[s], ac3, 0, 0, 0);
    }
    f4 acc = (ac0 + ac1) + (ac2 + ac3);
#pragma unroll
    for (int i = 0; i < 4; i++)
      pre[(gg * 4 + i) * 132 + wid * 16 + l15] = acc[i];
    asm volatile("s_waitcnt lgkmcnt(0)" ::: "memory");
    barrier_raw();  // BAR_c: pre ready

    // ---- gates: all 512 threads (16 rows x 32 units); shfl-pack h and
    // publish 8B per 4-lane leader directly (sc1 -> LLC)
    {
      f4 q = *(const f4*)&pre[grow * 132 + gu * 4];
      q += pv;
      float g_ = tanh_fast(q[0]);
      float i_ = sigm(q[1]);
      float f_ = sigm(q[2]);
      float o_ = sigm(q[3]);
      cst = g_ * i_ + cst * f_;
      float hv = tanh_fast(cst) * o_;
      if (t == T_STEPS - 1) {
        h32[(size_t)(rowbase + grow) * 1024 + ubase + gu] = hv;
      } else {
        union { _Float16 hh; unsigned short us; } cv;
        cv.hh = (_Float16)hv;
        unsigned v0 = cv.us;
        unsigned v1 = (unsigned)__shfl_down((int)v0, 1);
        unsigned lo = (v0 & 0xffffu) | (v1 << 16);
        unsigned lo2 = (unsigned)__shfl_down((int)lo, 2);
        if ((gu & 3) == 0) {
          ull_t pv8 = (ull_t)lo | ((ull_t)lo2 << 32);
          __hip_atomic_store((ull_t*)&hn[(size_t)(rowbase + grow) * 1024 + ubase + gu],
                             pv8, __ATOMIC_RELAXED, __HIP_MEMORY_SCOPE_AGENT);
        }
      }
    }
    if (t == T_STEPS - 1) break;

    // ---- per-wave drain + last-wave flag publish (no block barrier)
    asm volatile("s_waitcnt vmcnt(0)" ::: "memory");  // this wave's h stores at LLC
    __builtin_amdgcn_sched_barrier(0);
    if (lane == 0) {
      unsigned ret = atomicAdd(&scnt, 1u);  // LDS, monotone across steps
      if (ret == 8u * (unsigned)t + 7u)     // last of this step's 8 waves
        __hip_atomic_store(&flags[blk * FLAG_STRIDE], (unsigned)(t + 1),
                           __ATOMIC_RELAXED, __HIP_MEMORY_SCOPE_AGENT);
    }
  }
}

// ---------------- final projection p = h_T @ W_ph + b_p (fp32)
__global__ void proj(const float* __restrict__ h32, const float* __restrict__ Wph,
                     const float* __restrict__ bp, float* __restrict__ logits) {
  const int b = blockIdx.x >> 1;
  const int cc = (blockIdx.x & 1) * 256 + threadIdx.x;
  const float* hrow = h32 + b * 1024;
  float acc = bp[cc];
#pragma unroll 4
  for (int k = 0; k < 1024; k++) acc += hrow[k] * Wph[k * 512 + cc];
  logits[b * 512 + cc] = acc;
}

// ---------------- row-wise log_softmax
__global__ void lsm(const float* __restrict__ logits, float* __restrict__ out) {
  const int b = blockIdx.x;
  const int tid = threadIdx.x;
  __shared__ float sm[4];
  __shared__ float se[4];
  float v0 = logits[b * 512 + tid];
  float v1 = logits[b * 512 + 256 + tid];
  float m = fmaxf(v0, v1);
  for (int o = 1; o < 64; o <<= 1) m = fmaxf(m, __shfl_xor(m, o, 64));
  if ((tid & 63) == 0) sm[tid >> 6] = m;
  __syncthreads();
  m = fmaxf(fmaxf(sm[0], sm[1]), fmaxf(sm[2], sm[3]));
  float e = expf(v0 - m) + expf(v1 - m);
  for (int o = 1; o < 64; o <<= 1) e += __shfl_xor(e, o, 64);
  if ((tid & 63) == 0) se[tid >> 6] = e;
  __syncthreads();
  float ls = logf(se[0] + se[1] + se[2] + se[3]) + m;
  out[b * 512 + tid] = v0 - ls;
  out[b * 512 + 256 + tid] = v1 - ls;
}

extern "C" void kernel_launch(void* const* d_in, const int* in_sizes, int n_in,
                              void* d_out, int out_size, void* d_ws, size_t ws_size,
                              hipStream_t stream) {
  const int* x = (const int*)d_in[0];
  const float* emb = (const float*)d_in[1];
  const float* Wgx = (const float*)d_in[2];
  const float* Wgh = (const float*)d_in[3];
  const float* bg = (const float*)d_in[4];
  const float* Wix = (const float*)d_in[5];
  const float* Wih = (const float*)d_in[6];
  const float* bi = (const float*)d_in[7];
  const float* Wfx = (const float*)d_in[8];
  const float* Wfh = (const float*)d_in[9];
  const float* bf = (const float*)d_in[10];
  const float* Wox = (const float*)d_in[11];
  const float* Woh = (const float*)d_in[12];
  const float* bo = (const float*)d_in[13];
  const float* Wph = (const float*)d_in[14];
  const float* bp = (const float*)d_in[15];
  const float* h_init = (const float*)d_in[16];
  const float* c_init = (const float*)d_in[17];

  char* ws = (char*)d_ws;
  float* P = (float*)ws;                                   // 520*4096*4   = 8,519,680
  unsigned int* flags = (unsigned int*)(ws + (size_t)513 * 4096 * 4);  // 16 KB (P pad)
  _Float16* Wt = (_Float16*)(ws + 8519680);                // 4096*1024*2  = 8,388,608
  _Float16* hbuf = (_Float16*)(ws + 8519680 + 8388608);    // 2*128*1024*2 = 524,288
  float* h32 = (float*)(ws + 8519680 + 8388608 + 524288);  // 128*1024*4   = 524,288
  float* logits = (float*)(ws + 8519680 + 8388608 + 524288 + 524288);  // 128*512*4

  pack_P<<<dim3(65, 16), 256, 0, stream>>>(emb, Wgx, Wix, Wfx, Wox, bg, bi, bf, bo, P);
  pack_Wt<<<4096, 256, 0, stream>>>(Wgh, Wih, Wfh, Woh, Wt);

  void* args[] = {(void*)&x, (void*)&P, (void*)&Wt, (void*)&hbuf,
                  (void*)&h32, (void*)&h_init, (void*)&c_init, (void*)&flags};
  hipLaunchCooperativeKernel((void*)lstm_step_all, dim3(NBLK), dim3(512), args, 0, stream);

  proj<<<256, 256, 0, stream>>>(h32, Wph, bp, logits);
  lsm<<<128, 256, 0, stream>>>(logits, (float*)d_out);
}

// Round 16
// 1520.670 us; speedup vs baseline: 2.6337x; 1.3639x over previous
//
#include <hip/hip_runtime.h>
#include <hip/hip_cooperative_groups.h>
#include <cmath>

namespace cg = cooperative_groups;

#define T_STEPS 512
#define NBLK 256

typedef _Float16 h8 __attribute__((ext_vector_type(8)));
typedef float f4 __attribute__((ext_vector_type(4)));
typedef int i32x4 __attribute__((ext_vector_type(4)));
typedef unsigned long long ull_t;

__device__ __forceinline__ float sigm(float v) { return 1.f / (1.f + __expf(-v)); }
__device__ __forceinline__ float tanh_fast(float v) { return 1.f - 2.f / (__expf(2.f * v) + 1.f); }

// ---------------- pack P = emb @ [Wx interleaved] + bias : [513][4096] fp32 (exact input path)
__global__ void pack_P(const float* __restrict__ emb,
                       const float* __restrict__ Wgx, const float* __restrict__ Wix,
                       const float* __restrict__ Wfx, const float* __restrict__ Wox,
                       const float* __restrict__ bg, const float* __restrict__ bi,
                       const float* __restrict__ bf_, const float* __restrict__ bo,
                       float* __restrict__ P) {
  __shared__ float es[8][512];
  const int vg = blockIdx.x;   // 0..64
  const int st = blockIdx.y;   // 0..15
  const int tid = threadIdx.x;
  for (int i = tid; i < 8 * 512; i += 256) {
    int vv = i >> 9, k = i & 511;
    int v = vg * 8 + vv;
    es[vv][k] = (v < 513) ? emb[v * 512 + k] : 0.f;
  }
  __syncthreads();
  const int c = st * 256 + tid;
  const int gate = c & 3, unit = c >> 2;
  const float* W = gate == 0 ? Wgx : gate == 1 ? Wix : gate == 2 ? Wfx : Wox;
  const float* bias = gate == 0 ? bg : gate == 1 ? bi : gate == 2 ? bf_ : bo;
  float acc[8];
  const float bv = bias[unit];
#pragma unroll
  for (int vv = 0; vv < 8; vv++) acc[vv] = bv;
  for (int k = 0; k < 512; k++) {
    float w = W[k * 1024 + unit];
#pragma unroll
    for (int vv = 0; vv < 8; vv++) acc[vv] += es[vv][k] * w;
  }
#pragma unroll
  for (int vv = 0; vv < 8; vv++) {
    int v = vg * 8 + vv;
    if (v < 513) P[(size_t)v * 4096 + c] = acc[vv];
  }
}

// ---------------- pack Wt[c][k] = W_{gate(c)}h[k][unit(c)] as fp16
__global__ void pack_Wt(const float* __restrict__ Wgh, const float* __restrict__ Wih,
                        const float* __restrict__ Wfh, const float* __restrict__ Woh,
                        _Float16* __restrict__ Wt) {
  const int c = blockIdx.x;
  const int gate = c & 3, unit = c >> 2;
  const float* W = gate == 0 ? Wgh : gate == 1 ? Wih : gate == 2 ? Wfh : Woh;
  for (int k = threadIdx.x; k < 1024; k += 256)
    Wt[(size_t)c * 1024 + k] = (_Float16)W[k * 1024 + unit];
}

// ---------------- persistent LSTM: 8 independent row-groups of 16 batch rows.
// SYNC = LSB STEP-TAGS IN THE DATA (seqlock style), no flags/polls/drains:
//  * h_t lives in buffer t&1; every fp16's mantissa LSB = tag_t = (t>>1)&1
//    (alternates on each buffer reuse; <=1 ulp noise, well inside budget).
//  * producer (gates): set LSB=tag_{t+1}, store 8B sc1, DONE (no drain/flag).
//  * consumer (A-stage): load 4x dwordx4 sc0 sc1, accept iff all 16 LSBs per
//    chunk == tag_t; else sleep+retry. One LLC RTT producer->consumer.
//  * WAR/drift: publishing h_{t+2} requires having read all h_{t+1}, whose
//    producers read all h_t first => drift <= 1 buffer; overwritten data has
//    the other tag so stale acceptance is impossible.
//  * init: h0 (tag 0) into buf0; TAG-1 JUNK (0x0001) into buf1 (the 0xAA ws
//    poison has LSB 0 = tag of t=1 -- must be overwritten!). grid.sync covers
//    t=0. Replays: leftovers are tag-1 (h510/h511) -> re-junk/overwrite is
//    deterministic.
// Per step: x/P gather -> tag-verified A-load+LDS stage -> BAR -> 32 MFMA ->
// pre scatter -> BAR -> gates + tag + shfl-pack sc1 publish. 2 barriers/step.
__launch_bounds__(512, 2)
__global__ void lstm_step_all(const int* __restrict__ x,
                              const float* __restrict__ P,
                              const _Float16* __restrict__ Wt,
                              _Float16* __restrict__ hbuf,
                              float* __restrict__ h32,
                              const float* __restrict__ h_init,
                              const float* __restrict__ c_init) {
  cg::grid_group grid = cg::this_grid();
  __shared__ _Float16 alds[16 * 1024];   // 32 KB staged A (granule-XOR swizzled)
  __shared__ float pre[16 * 132];        // 8.25 KB fp32 pre-activations
  const int tid = threadIdx.x;
  const int blk = blockIdx.x;
  const int grp = blk & 7;      // row-group
  const int sub = blk >> 3;     // 0..31 col-partition
  const int lane = tid & 63;
  const int wid = tid >> 6;
  const int l15 = lane & 15;
  const int gg = lane >> 4;
  const int kg = gg * 8;
  const int colbase = sub * 128;  // gate-col base
  const int ubase = sub * 32;     // hidden-unit base
  const int rowbase = grp * 16;   // batch-row base
  const int arow = tid >> 5;      // staging row (0..15), 32 threads per row
  const int agb = tid & 31;       // staging granule base (16B granules)

  // B resident in VGPRs: wave w covers cols colbase + w*16 .. +16, all K
  h8 bfr[32];
  {
    const _Float16* wp = Wt + (size_t)(colbase + wid * 16 + l15) * 1024 + kg;
#pragma unroll
    for (int s = 0; s < 32; s++) bfr[s] = *(const h8*)(wp + s * 32);
  }

  // init: h0 (LSB cleared -> tag 0) into buffer 0; tag-1 junk into buffer 1
  if (tid < 128) {
    int r16 = tid >> 3, q = tid & 7;
    union { _Float16 h[4]; ull_t u; } pk;
#pragma unroll
    for (int u = 0; u < 4; u++) pk.h[u] = (_Float16)h_init[ubase + q * 4 + u];
    pk.u &= 0xFFFEFFFEFFFEFFFEull;  // force tag 0
    *(ull_t*)&hbuf[(size_t)(rowbase + r16) * 1024 + ubase + q * 4] = pk.u;
    // buffer 1: junk with tag 1 so t=1 readers reject until real h1 lands
    *(ull_t*)&hbuf[(size_t)(128 * 1024) + (size_t)(rowbase + r16) * 1024 + ubase + q * 4] =
        0x0001000100010001ull;
  }
  // gate-phase identity: row = tid>>5, unit = tid&31 (persistent c state)
  const int grow = tid >> 5;
  const int gu = tid & 31;
  float cst = c_init[ubase + gu];
  // swizzled LDS base for staging writes (granule XOR on low 3 bits)
  const int abase = arow * 1024 + ((agb ^ (arow & 7)) * 8);
  grid.sync();  // covers h0/junk, Wt/P reads

  for (int t = 0; t < T_STEPS; t++) {
    const _Float16* hc = hbuf + (t & 1) * (128 * 1024);
    _Float16* hn = hbuf + ((t + 1) & 1) * (128 * 1024);

    // exact-P gather issued early (x then P, cache-warm plain loads)
    const int xv = x[(rowbase + grow) * 513 + t];
    const float* prow = P + (size_t)xv * 4096 + colbase + gu * 4;
    f4 pv = *(const f4*)(prow);

    // ---- A-stage with tag verification (the only inter-block sync)
    const int tagm = (int)(0x00010001u * (unsigned)((t >> 1) & 1));
    i32x4 av0, av1, av2, av3;
    {
      const _Float16* pbase = &hc[(size_t)(rowbase + arow) * 1024 + agb * 8];
      for (;;) {
        asm volatile("global_load_dwordx4 %0, %1, off sc0 sc1"
                     : "=v"(av0) : "v"(pbase) : "memory");
        asm volatile("global_load_dwordx4 %0, %1, off offset:512 sc0 sc1"
                     : "=v"(av1) : "v"(pbase) : "memory");
        asm volatile("global_load_dwordx4 %0, %1, off offset:1024 sc0 sc1"
                     : "=v"(av2) : "v"(pbase) : "memory");
        asm volatile("global_load_dwordx4 %0, %1, off offset:1536 sc0 sc1"
                     : "=v"(av3) : "v"(pbase) : "memory");
        asm volatile("s_waitcnt vmcnt(0)" ::: "memory");
        bool ok = true;
#pragma unroll
        for (int j = 0; j < 4; j++) {
          ok &= ((av0[j] & 0x00010001) == tagm);
          ok &= ((av1[j] & 0x00010001) == tagm);
          ok &= ((av2[j] & 0x00010001) == tagm);
          ok &= ((av3[j] & 0x00010001) == tagm);
        }
        if (ok) break;
        __builtin_amdgcn_s_sleep(1);
      }
    }
    __builtin_amdgcn_sched_barrier(0);
    *(i32x4*)&alds[abase] = av0;
    *(i32x4*)&alds[abase + 256] = av1;  // +32 granules = +256 fp16
    *(i32x4*)&alds[abase + 512] = av2;
    *(i32x4*)&alds[abase + 768] = av3;
    __syncthreads();  // BAR1: alds ready (vmcnt/lgkm drains are already satisfied)

    // ---- MFMA: 16 rows x 16 cols x K=1024, B from regs, 4 acc chains
    f4 ac0 = {0.f, 0.f, 0.f, 0.f}, ac1 = ac0, ac2 = ac0, ac3 = ac0;
#pragma unroll
    for (int s = 0; s < 32; s++) {
      int g = s * 4 + gg;
      h8 a = *(const h8*)&alds[l15 * 1024 + ((g ^ (l15 & 7)) * 8)];
      if ((s & 3) == 0) ac0 = __builtin_amdgcn_mfma_f32_16x16x32_f16(a, bfr[s], ac0, 0, 0, 0);
      else if ((s & 3) == 1) ac1 = __builtin_amdgcn_mfma_f32_16x16x32_f16(a, bfr[s], ac1, 0, 0, 0);
      else if ((s & 3) == 2) ac2 = __builtin_amdgcn_mfma_f32_16x16x32_f16(a, bfr[s], ac2, 0, 0, 0);
      else ac3 = __builtin_amdgcn_mfma_f32_16x16x32_f16(a, bfr[s], ac3, 0, 0, 0);
    }
    f4 acc = (ac0 + ac1) + (ac2 + ac3);
#pragma unroll
    for (int i = 0; i < 4; i++)
      pre[(gg * 4 + i) * 132 + wid * 16 + l15] = acc[i];
    __syncthreads();  // BAR2: pre ready

    // ---- gates: all 512 threads (16 rows x 32 units); tag LSB, shfl-pack,
    // publish 8B per 4-lane leader (sc1). No drain, no flag.
    {
      f4 q = *(const f4*)&pre[grow * 132 + gu * 4];
      q += pv;
      float g_ = tanh_fast(q[0]);
      float i_ = sigm(q[1]);
      float f_ = sigm(q[2]);
      float o_ = sigm(q[3]);
      cst = g_ * i_ + cst * f_;
      float hv = tanh_fast(cst) * o_;
      if (t == T_STEPS - 1) {
        h32[(size_t)(rowbase + grow) * 1024 + ubase + gu] = hv;
      } else {
        const unsigned tagn = (unsigned)(((t + 1) >> 1) & 1);
        union { _Float16 hh; unsigned short us; } cv;
        cv.hh = (_Float16)hv;
        unsigned v0 = ((unsigned)cv.us & 0xFFFEu) | tagn;
        unsigned v1 = (unsigned)__shfl_down((int)v0, 1);
        unsigned lo = (v0 & 0xffffu) | (v1 << 16);
        unsigned lo2 = (unsigned)__shfl_down((int)lo, 2);
        if ((gu & 3) == 0) {
          ull_t pv8 = (ull_t)lo | ((ull_t)lo2 << 32);
          __hip_atomic_store((ull_t*)&hn[(size_t)(rowbase + grow) * 1024 + ubase + gu],
                             pv8, __ATOMIC_RELAXED, __HIP_MEMORY_SCOPE_AGENT);
        }
      }
    }
  }
}

// ---------------- final projection p = h_T @ W_ph + b_p (fp32)
__global__ void proj(const float* __restrict__ h32, const float* __restrict__ Wph,
                     const float* __restrict__ bp, float* __restrict__ logits) {
  const int b = blockIdx.x >> 1;
  const int cc = (blockIdx.x & 1) * 256 + threadIdx.x;
  const float* hrow = h32 + b * 1024;
  float acc = bp[cc];
#pragma unroll 4
  for (int k = 0; k < 1024; k++) acc += hrow[k] * Wph[k * 512 + cc];
  logits[b * 512 + cc] = acc;
}

// ---------------- row-wise log_softmax
__global__ void lsm(const float* __restrict__ logits, float* __restrict__ out) {
  const int b = blockIdx.x;
  const int tid = threadIdx.x;
  __shared__ float sm[4];
  __shared__ float se[4];
  float v0 = logits[b * 512 + tid];
  float v1 = logits[b * 512 + 256 + tid];
  float m = fmaxf(v0, v1);
  for (int o = 1; o < 64; o <<= 1) m = fmaxf(m, __shfl_xor(m, o, 64));
  if ((tid & 63) == 0) sm[tid >> 6] = m;
  __syncthreads();
  m = fmaxf(fmaxf(sm[0], sm[1]), fmaxf(sm[2], sm[3]));
  float e = expf(v0 - m) + expf(v1 - m);
  for (int o = 1; o < 64; o <<= 1) e += __shfl_xor(e, o, 64);
  if ((tid & 63) == 0) se[tid >> 6] = e;
  __syncthreads();
  float ls = logf(se[0] + se[1] + se[2] + se[3]) + m;
  out[b * 512 + tid] = v0 - ls;
  out[b * 512 + 256 + tid] = v1 - ls;
}

extern "C" void kernel_launch(void* const* d_in, const int* in_sizes, int n_in,
                              void* d_out, int out_size, void* d_ws, size_t ws_size,
                              hipStream_t stream) {
  const int* x = (const int*)d_in[0];
  const float* emb = (const float*)d_in[1];
  const float* Wgx = (const float*)d_in[2];
  const float* Wgh = (const float*)d_in[3];
  const float* bg = (const float*)d_in[4];
  const float* Wix = (const float*)d_in[5];
  const float* Wih = (const float*)d_in[6];
  const float* bi = (const float*)d_in[7];
  const float* Wfx = (const float*)d_in[8];
  const float* Wfh = (const float*)d_in[9];
  const float* bf = (const float*)d_in[10];
  const float* Wox = (const float*)d_in[11];
  const float* Woh = (const float*)d_in[12];
  const float* bo = (const float*)d_in[13];
  const float* Wph = (const float*)d_in[14];
  const float* bp = (const float*)d_in[15];
  const float* h_init = (const float*)d_in[16];
  const float* c_init = (const float*)d_in[17];

  char* ws = (char*)d_ws;
  float* P = (float*)ws;                                   // 520*4096*4   = 8,519,680
  _Float16* Wt = (_Float16*)(ws + 8519680);                // 4096*1024*2  = 8,388,608
  _Float16* hbuf = (_Float16*)(ws + 8519680 + 8388608);    // 2*128*1024*2 = 524,288
  float* h32 = (float*)(ws + 8519680 + 8388608 + 524288);  // 128*1024*4   = 524,288
  float* logits = (float*)(ws + 8519680 + 8388608 + 524288 + 524288);  // 128*512*4

  pack_P<<<dim3(65, 16), 256, 0, stream>>>(emb, Wgx, Wix, Wfx, Wox, bg, bi, bf, bo, P);
  pack_Wt<<<4096, 256, 0, stream>>>(Wgh, Wih, Wfh, Woh, Wt);

  void* args[] = {(void*)&x, (void*)&P, (void*)&Wt, (void*)&hbuf,
                  (void*)&h32, (void*)&h_init, (void*)&c_init};
  hipLaunchCooperativeKernel((void*)lstm_step_all, dim3(NBLK), dim3(512), args, 0, stream);

  proj<<<256, 256, 0, stream>>>(h32, Wph, bp, logits);
  lsm<<<128, 256, 0, stream>>>(logits, (float*)d_out);
}

// Round 17
// 1387.045 us; speedup vs baseline: 2.8874x; 1.0963x over previous
//
#include <hip/hip_runtime.h>
#include <hip/hip_cooperative_groups.h>
#include <cmath>

namespace cg = cooperative_groups;

#define T_STEPS 512
#define NBLK 256

typedef _Float16 h8 __attribute__((ext_vector_type(8)));
typedef float f4 __attribute__((ext_vector_type(4)));
typedef int i32x4 __attribute__((ext_vector_type(4)));
typedef unsigned long long ull_t;

__device__ __forceinline__ float sigm(float v) { return 1.f / (1.f + __expf(-v)); }
__device__ __forceinline__ float tanh_fast(float v) { return 1.f - 2.f / (__expf(2.f * v) + 1.f); }

// ---------------- pack P = emb @ [Wx interleaved] + bias : [513][4096] fp32 (exact input path)
__global__ void pack_P(const float* __restrict__ emb,
                       const float* __restrict__ Wgx, const float* __restrict__ Wix,
                       const float* __restrict__ Wfx, const float* __restrict__ Wox,
                       const float* __restrict__ bg, const float* __restrict__ bi,
                       const float* __restrict__ bf_, const float* __restrict__ bo,
                       float* __restrict__ P) {
  __shared__ float es[8][512];
  const int vg = blockIdx.x;   // 0..64
  const int st = blockIdx.y;   // 0..15
  const int tid = threadIdx.x;
  for (int i = tid; i < 8 * 512; i += 256) {
    int vv = i >> 9, k = i & 511;
    int v = vg * 8 + vv;
    es[vv][k] = (v < 513) ? emb[v * 512 + k] : 0.f;
  }
  __syncthreads();
  const int c = st * 256 + tid;
  const int gate = c & 3, unit = c >> 2;
  const float* W = gate == 0 ? Wgx : gate == 1 ? Wix : gate == 2 ? Wfx : Wox;
  const float* bias = gate == 0 ? bg : gate == 1 ? bi : gate == 2 ? bf_ : bo;
  float acc[8];
  const float bv = bias[unit];
#pragma unroll
  for (int vv = 0; vv < 8; vv++) acc[vv] = bv;
  for (int k = 0; k < 512; k++) {
    float w = W[k * 1024 + unit];
#pragma unroll
    for (int vv = 0; vv < 8; vv++) acc[vv] += es[vv][k] * w;
  }
#pragma unroll
  for (int vv = 0; vv < 8; vv++) {
    int v = vg * 8 + vv;
    if (v < 513) P[(size_t)v * 4096 + c] = acc[vv];
  }
}

// ---------------- pack Wt[c][k] = W_{gate(c)}h[k][unit(c)] as fp16
__global__ void pack_Wt(const float* __restrict__ Wgh, const float* __restrict__ Wih,
                        const float* __restrict__ Wfh, const float* __restrict__ Woh,
                        _Float16* __restrict__ Wt) {
  const int c = blockIdx.x;
  const int gate = c & 3, unit = c >> 2;
  const float* W = gate == 0 ? Wgh : gate == 1 ? Wih : gate == 2 ? Wfh : Woh;
  for (int k = threadIdx.x; k < 1024; k += 256)
    Wt[(size_t)c * 1024 + k] = (_Float16)W[k * 1024 + unit];
}

// ---------------- persistent LSTM: 8 independent row-groups of 16 batch rows.
// Sync = R16's LSB step-tag seqlock (verbatim). NEW: SPLIT-K ACROSS WAVES.
// Wave w owns K-slice [128w,128w+128) for ALL 128 cols (8 col-tiles):
//  * A-reads from LDS drop from 8x32KB (every wave read every row) to
//    8x4KB -- the 8x redundancy that saturated the LDS pipe is gone.
//  * MFMA operands SWAPPED: mfma(Wt_frag, h_frag, acc) computes the
//    transposed C/D tile, so each lane holds 4 CONSECUTIVE output cols of
//    one row -> fp32 partials store as one ds_write_b128 into
//    part[w][row][col], and the gate threads' 8-way reduce reads b128 at
//    the same (grow,gu) identity as R16.
// Barriers: BAR1 (post-stage), BAR2 (post-part-write). WAR safety:
//  * alds: stage(t+1) follows BAR2(t) [via publish->verify path]; all MFMA
//    hfr reads of alds(t) precede BAR2(t).  * part: writes(t+1) follow
//    BAR1(t+1); reduce reads(t) precede publish(t) < BAR1(t+1).
__launch_bounds__(512, 2)
__global__ void lstm_step_all(const int* __restrict__ x,
                              const float* __restrict__ P,
                              const _Float16* __restrict__ Wt,
                              _Float16* __restrict__ hbuf,
                              float* __restrict__ h32,
                              const float* __restrict__ h_init,
                              const float* __restrict__ c_init) {
  cg::grid_group grid = cg::this_grid();
  __shared__ _Float16 alds[16 * 1024];   // 32 KB staged A (granule-XOR swizzled)
  __shared__ float part[8 * 16 * 132];   // 67.6 KB split-K partials
  const int tid = threadIdx.x;
  const int blk = blockIdx.x;
  const int grp = blk & 7;      // row-group
  const int sub = blk >> 3;     // 0..31 col-partition
  const int lane = tid & 63;
  const int wid = tid >> 6;     // wave = K-slice owner
  const int l15 = lane & 15;
  const int gg = lane >> 4;
  const int kg = gg * 8;
  const int colbase = sub * 128;  // gate-col base
  const int ubase = sub * 32;     // hidden-unit base
  const int rowbase = grp * 16;   // batch-row base
  const int arow = tid >> 5;      // staging row (0..15), 32 threads per row
  const int agb = tid & 31;       // staging granule base (16B granules)

  // Wt fragments (used as the MFMA *A* operand): wave w, col-tile ct, k-step ks
  h8 wfr[32];
  {
    const _Float16* wp = Wt + (size_t)(colbase + l15) * 1024 + wid * 128 + kg;
#pragma unroll
    for (int ct = 0; ct < 8; ct++)
#pragma unroll
      for (int ks = 0; ks < 4; ks++)
        wfr[ct * 4 + ks] = *(const h8*)(wp + (size_t)ct * 16 * 1024 + ks * 32);
  }

  // init: h0 (LSB cleared -> tag 0) into buffer 0; tag-1 junk into buffer 1
  if (tid < 128) {
    int r16 = tid >> 3, q = tid & 7;
    union { _Float16 h[4]; ull_t u; } pk;
#pragma unroll
    for (int u = 0; u < 4; u++) pk.h[u] = (_Float16)h_init[ubase + q * 4 + u];
    pk.u &= 0xFFFEFFFEFFFEFFFEull;  // force tag 0
    *(ull_t*)&hbuf[(size_t)(rowbase + r16) * 1024 + ubase + q * 4] = pk.u;
    *(ull_t*)&hbuf[(size_t)(128 * 1024) + (size_t)(rowbase + r16) * 1024 + ubase + q * 4] =
        0x0001000100010001ull;  // buffer 1: tag-1 junk (ws poison has LSB 0!)
  }
  // gate-phase identity: row = tid>>5, unit = tid&31 (persistent c state)
  const int grow = tid >> 5;
  const int gu = tid & 31;
  float cst = c_init[ubase + gu];
  // swizzled LDS base for staging writes (granule XOR on low 3 bits)
  const int abase = arow * 1024 + ((agb ^ (arow & 7)) * 8);
  grid.sync();  // covers h0/junk, Wt/P reads

  for (int t = 0; t < T_STEPS; t++) {
    const _Float16* hc = hbuf + (t & 1) * (128 * 1024);
    _Float16* hn = hbuf + ((t + 1) & 1) * (128 * 1024);

    // exact-P gather issued early (x then P, cache-warm plain loads)
    const int xv = x[(rowbase + grow) * 513 + t];
    const float* prow = P + (size_t)xv * 4096 + colbase + gu * 4;
    f4 pv = *(const f4*)(prow);

    // ---- A-stage with tag verification (the only inter-block sync)
    const int tagm = (int)(0x00010001u * (unsigned)((t >> 1) & 1));
    i32x4 av0, av1, av2, av3;
    {
      const _Float16* pbase = &hc[(size_t)(rowbase + arow) * 1024 + agb * 8];
      for (;;) {
        asm volatile("global_load_dwordx4 %0, %1, off sc0 sc1"
                     : "=v"(av0) : "v"(pbase) : "memory");
        asm volatile("global_load_dwordx4 %0, %1, off offset:512 sc0 sc1"
                     : "=v"(av1) : "v"(pbase) : "memory");
        asm volatile("global_load_dwordx4 %0, %1, off offset:1024 sc0 sc1"
                     : "=v"(av2) : "v"(pbase) : "memory");
        asm volatile("global_load_dwordx4 %0, %1, off offset:1536 sc0 sc1"
                     : "=v"(av3) : "v"(pbase) : "memory");
        asm volatile("s_waitcnt vmcnt(0)" ::: "memory");
        bool ok = true;
#pragma unroll
        for (int j = 0; j < 4; j++) {
          ok &= ((av0[j] & 0x00010001) == tagm);
          ok &= ((av1[j] & 0x00010001) == tagm);
          ok &= ((av2[j] & 0x00010001) == tagm);
          ok &= ((av3[j] & 0x00010001) == tagm);
        }
        if (ok) break;
        __builtin_amdgcn_s_sleep(1);
      }
    }
    __builtin_amdgcn_sched_barrier(0);
    *(i32x4*)&alds[abase] = av0;
    *(i32x4*)&alds[abase + 256] = av1;  // +32 granules = +256 fp16
    *(i32x4*)&alds[abase + 512] = av2;
    *(i32x4*)&alds[abase + 768] = av3;
    __syncthreads();  // BAR1: alds ready

    // ---- h fragments (MFMA *B* operand): wave's own K-slice only, 4 b128
    h8 hfr[4];
#pragma unroll
    for (int ks = 0; ks < 4; ks++) {
      int g = wid * 16 + ks * 4 + gg;
      hfr[ks] = *(const h8*)&alds[l15 * 1024 + ((g ^ (l15 & 7)) * 8)];
    }

    // ---- MFMA, operands swapped: acc[ct][i] = pre[row l15][col ct*16+4gg+i]
    f4 acc[8];
#pragma unroll
    for (int ct = 0; ct < 8; ct++) {
      acc[ct] = (f4){0.f, 0.f, 0.f, 0.f};
#pragma unroll
      for (int ks = 0; ks < 4; ks++)
        acc[ct] = __builtin_amdgcn_mfma_f32_16x16x32_f16(wfr[ct * 4 + ks], hfr[ks],
                                                         acc[ct], 0, 0, 0);
    }
    // partial store: one b128 per col-tile (4 consecutive cols of row l15)
#pragma unroll
    for (int ct = 0; ct < 8; ct++)
      *(f4*)&part[(wid * 16 + l15) * 132 + ct * 16 + 4 * gg] = acc[ct];
    __syncthreads();  // BAR2: partials ready

    // ---- reduce + gates: thread (grow, gu) sums 8 K-slices + exact-P
    {
      f4 q = pv;
#pragma unroll
      for (int w = 0; w < 8; w++)
        q += *(const f4*)&part[(w * 16 + grow) * 132 + gu * 4];
      float g_ = tanh_fast(q[0]);
      float i_ = sigm(q[1]);
      float f_ = sigm(q[2]);
      float o_ = sigm(q[3]);
      cst = g_ * i_ + cst * f_;
      float hv = tanh_fast(cst) * o_;
      if (t == T_STEPS - 1) {
        h32[(size_t)(rowbase + grow) * 1024 + ubase + gu] = hv;
      } else {
        const unsigned tagn = (unsigned)(((t + 1) >> 1) & 1);
        union { _Float16 hh; unsigned short us; } cv;
        cv.hh = (_Float16)hv;
        unsigned v0 = ((unsigned)cv.us & 0xFFFEu) | tagn;
        unsigned v1 = (unsigned)__shfl_down((int)v0, 1);
        unsigned lo = (v0 & 0xffffu) | (v1 << 16);
        unsigned lo2 = (unsigned)__shfl_down((int)lo, 2);
        if ((gu & 3) == 0) {
          ull_t pv8 = (ull_t)lo | ((ull_t)lo2 << 32);
          __hip_atomic_store((ull_t*)&hn[(size_t)(rowbase + grow) * 1024 + ubase + gu],
                             pv8, __ATOMIC_RELAXED, __HIP_MEMORY_SCOPE_AGENT);
        }
      }
    }
  }
}

// ---------------- final projection p = h_T @ W_ph + b_p (fp32)
__global__ void proj(const float* __restrict__ h32, const float* __restrict__ Wph,
                     const float* __restrict__ bp, float* __restrict__ logits) {
  const int b = blockIdx.x >> 1;
  const int cc = (blockIdx.x & 1) * 256 + threadIdx.x;
  const float* hrow = h32 + b * 1024;
  float acc = bp[cc];
#pragma unroll 4
  for (int k = 0; k < 1024; k++) acc += hrow[k] * Wph[k * 512 + cc];
  logits[b * 512 + cc] = acc;
}

// ---------------- row-wise log_softmax
__global__ void lsm(const float* __restrict__ logits, float* __restrict__ out) {
  const int b = blockIdx.x;
  const int tid = threadIdx.x;
  __shared__ float sm[4];
  __shared__ float se[4];
  float v0 = logits[b * 512 + tid];
  float v1 = logits[b * 512 + 256 + tid];
  float m = fmaxf(v0, v1);
  for (int o = 1; o < 64; o <<= 1) m = fmaxf(m, __shfl_xor(m, o, 64));
  if ((tid & 63) == 0) sm[tid >> 6] = m;
  __syncthreads();
  m = fmaxf(fmaxf(sm[0], sm[1]), fmaxf(sm[2], sm[3]));
  float e = expf(v0 - m) + expf(v1 - m);
  for (int o = 1; o < 64; o <<= 1) e += __shfl_xor(e, o, 64);
  if ((tid & 63) == 0) se[tid >> 6] = e;
  __syncthreads();
  float ls = logf(se[0] + se[1] + se[2] + se[3]) + m;
  out[b * 512 + tid] = v0 - ls;
  out[b * 512 + 256 + tid] = v1 - ls;
}

extern "C" void kernel_launch(void* const* d_in, const int* in_sizes, int n_in,
                              void* d_out, int out_size, void* d_ws, size_t ws_size,
                              hipStream_t stream) {
  const int* x = (const int*)d_in[0];
  const float* emb = (const float*)d_in[1];
  const float* Wgx = (const float*)d_in[2];
  const float* Wgh = (const float*)d_in[3];
  const float* bg = (const float*)d_in[4];
  const float* Wix = (const float*)d_in[5];
  const float* Wih = (const float*)d_in[6];
  const float* bi = (const float*)d_in[7];
  const float* Wfx = (const float*)d_in[8];
  const float* Wfh = (const float*)d_in[9];
  const float* bf = (const float*)d_in[10];
  const float* Wox = (const float*)d_in[11];
  const float* Woh = (const float*)d_in[12];
  const float* bo = (const float*)d_in[13];
  const float* Wph = (const float*)d_in[14];
  const float* bp = (const float*)d_in[15];
  const float* h_init = (const float*)d_in[16];
  const float* c_init = (const float*)d_in[17];

  char* ws = (char*)d_ws;
  float* P = (float*)ws;                                   // 520*4096*4   = 8,519,680
  _Float16* Wt = (_Float16*)(ws + 8519680);                // 4096*1024*2  = 8,388,608
  _Float16* hbuf = (_Float16*)(ws + 8519680 + 8388608);    // 2*128*1024*2 = 524,288
  float* h32 = (float*)(ws + 8519680 + 8388608 + 524288);  // 128*1024*4   = 524,288
  float* logits = (float*)(ws + 8519680 + 8388608 + 524288 + 524288);  // 128*512*4

  pack_P<<<dim3(65, 16), 256, 0, stream>>>(emb, Wgx, Wix, Wfx, Wox, bg, bi, bf, bo, P);
  pack_Wt<<<4096, 256, 0, stream>>>(Wgh, Wih, Wfh, Woh, Wt);

  void* args[] = {(void*)&x, (void*)&P, (void*)&Wt, (void*)&hbuf,
                  (void*)&h32, (void*)&h_init, (void*)&c_init};
  hipLaunchCooperativeKernel((void*)lstm_step_all, dim3(NBLK), dim3(512), args, 0, stream);

  proj<<<256, 256, 0, stream>>>(h32, Wph, bp, logits);
  lsm<<<128, 256, 0, stream>>>(logits, (float*)d_out);
}